// Round 11
// baseline (119.473 us; speedup 1.0000x reference)
//
#include <hip/hip_runtime.h>

// out[b,n,f] = lo[f]*x[b,n,f-1] + hi[f]*x[b,n,f+1]
// lo[f] = adj_t[f, f-1] (f>=1 else 0), hi[f] = adj_t[f, f+1] (f<=T-2 else 0)
// B=64, N=512, T=512. Memory-bound band stencil: 134 MB traffic -> ~21 us floor.
//
// Single fused kernel: each block extracts the two off-diagonals of adj_t
// into a 4 KB LDS table once (adj is 1 MB -> L2-served after the first
// blocks), then hoists its two float4 coefficients into registers.
// Hoisting is legal because grid-stride = gridDim.x*256 is a multiple of
// 128 vec/row, so each thread's in-row position f4 is loop-invariant.

#define T_DIM 512

__global__ __launch_bounds__(256) void band_stencil_fused(
        const float* __restrict__ x,
        const float* __restrict__ adj,
        float* __restrict__ out,
        long total_vec /* B*N*T/4 */) {
    __shared__ __align__(16) float lo_s[T_DIM];
    __shared__ __align__(16) float hi_s[T_DIM];

    // Build coefficient table (4 scattered L2-hit loads per thread, once).
    for (int f = threadIdx.x; f < T_DIM; f += 256) {
        lo_s[f] = (f >= 1)         ? adj[(size_t)f * T_DIM + (f - 1)] : 0.0f;
        hi_s[f] = (f < T_DIM - 1)  ? adj[(size_t)f * T_DIM + (f + 1)] : 0.0f;
    }
    __syncthreads();

    const int lane = threadIdx.x & 63;
    const long stride = (long)gridDim.x * blockDim.x;   // multiple of 128
    const long total_elems = total_vec * 4;
    const long v0 = (long)blockIdx.x * blockDim.x + threadIdx.x;

    // Loop-invariant coefficients -> registers.
    const int f4 = (int)(v0 & (T_DIM / 4 - 1));
    const float4 lo = ((const float4*)lo_s)[f4];
    const float4 hi = ((const float4*)hi_s)[f4];

    const float4* __restrict__ x4 = (const float4*)x;
    float4* __restrict__ o4 = (float4*)out;

    // Pure-copy memory pattern: 1 float4 load + 1 float4 store per iter.
    // Neighbors via cross-lane shuffle; only wave-edge lanes touch memory.
    for (long v = v0; v < total_vec; v += stride) {
        float4 xv = x4[v];

        float xm1 = __shfl_up(xv.w, 1);        // lane-1's last elem  = x[g-1]
        float xp4 = __shfl_down(xv.x, 1);      // lane+1's first elem = x[g+4]

        long g = v * 4;
        if (lane == 0)
            xm1 = (g > 0) ? x[g - 1] : 0.0f;
        if (lane == 63 || v == total_vec - 1)
            xp4 = (g + 4 < total_elems) ? x[g + 4] : 0.0f;

        // Cross-row leakage at f=0 / f=T-1 is killed by lo[0]=0 / hi[T-1]=0.
        float4 o;
        o.x = lo.x * xm1  + hi.x * xv.y;
        o.y = lo.y * xv.x + hi.y * xv.z;
        o.z = lo.z * xv.y + hi.z * xv.w;
        o.w = lo.w * xv.z + hi.w * xp4;
        o4[v] = o;
    }
}

extern "C" void kernel_launch(void* const* d_in, const int* in_sizes, int n_in,
                              void* d_out, int out_size, void* d_ws, size_t ws_size,
                              hipStream_t stream) {
    const float* x   = (const float*)d_in[0];   // [B, N, T] fp32
    const float* adj = (const float*)d_in[1];   // [T, T] fp32
    float* out = (float*)d_out;                 // [B, N, T] fp32
    (void)d_ws; (void)ws_size;

    long total_vec = (long)out_size / 4;        // 4,194,304
    int nblocks = (int)((total_vec + 255) / 256);
    if (nblocks > 2048) nblocks = 2048;         // 8 blocks/CU, grid-stride x8
    band_stencil_fused<<<nblocks, 256, 0, stream>>>(x, adj, out, total_vec);
}